// Round 14
// baseline (313.292 us; speedup 1.0000x reference)
//
#include <hip/hip_runtime.h>
#include <math.h>

#define Bsz 4
#define Sq  2048
#define Eq  1024
#define Hh  16
#define DHd 64
#define Kb  9
#define LOG2E 1.44269504088896340736f
#define NCLS 10  // row classes: query(-1) + pids 0..8

typedef _Float16 f16;
typedef __attribute__((ext_vector_type(8))) _Float16 fh8;   // MFMA A/B frag (4 VGPRs)
typedef __attribute__((ext_vector_type(4))) _Float16 fh4;
typedef __attribute__((ext_vector_type(2))) _Float16 fh2;
typedef __attribute__((ext_vector_type(4))) float fx4;      // 16x16 C/D frag
typedef __attribute__((ext_vector_type(16))) float fx16;    // 32x32 C/D frag
typedef __attribute__((ext_vector_type(4))) int i4;

// LDS swizzle: 64-half rows (128 B) -> XOR row into 16B-chunk index.
#define SWZ(r, c) ((r) * 64 + ((c) ^ (((r) & 7) << 3)))

static __device__ __forceinline__ float fexp2(float x) {
#if __has_builtin(__builtin_amdgcn_exp2f)
  return __builtin_amdgcn_exp2f(x);   // raw v_exp_f32
#else
  return __expf(x * 0.6931471805599453f);
#endif
}

// ---------------------------------------------------------------------------
// prep: fused pid/lfTab build + fp32->fp16 casts of hs, wi, wo (one launch).
// ---------------------------------------------------------------------------
__global__ __launch_bounds__(256) void prep(
    const float* __restrict__ hs, f16* __restrict__ hsf,
    const float* __restrict__ wi, f16* __restrict__ wif,
    const float* __restrict__ wo, f16* __restrict__ wof,
    const int* __restrict__ bnd, const float* __restrict__ rel,
    int* __restrict__ pidr, float* __restrict__ lfTab) {
  const int bid = blockIdx.x;
  if (bid < 6144) {
    const float* src;
    f16* dst;
    int off;
    if (bid < 4096)      { src = hs; dst = hsf; off = bid; }
    else if (bid < 5632) { src = wi; dst = wif; off = bid - 4096; }
    else                 { src = wo; dst = wof; off = bid - 5632; }
    int i = (off * 256 + threadIdx.x) * 8;
    float4 a = *(const float4*)&src[i];
    float4 b = *(const float4*)&src[i + 4];
    fh8 o;
    o[0] = (f16)a.x; o[1] = (f16)a.y; o[2] = (f16)a.z; o[3] = (f16)a.w;
    o[4] = (f16)b.x; o[5] = (f16)b.y; o[6] = (f16)b.z; o[7] = (f16)b.w;
    *(fh8*)&dst[i] = o;
  } else {
    int idx = (bid - 6144) * 256 + threadIdx.x;
    if (idx >= Bsz * Sq) return;
    int b = idx >> 11;
    int s = idx & (Sq - 1);
    int j = -1;
#pragma unroll
    for (int t = 0; t < Kb; ++t) {
      if (bnd[b * Kb + t] <= s) j = t;
    }
    pidr[idx] = j;
    bool inp = (j >= 0 && j < Kb - 1);
    float cv = inp ? rel[b * (Kb - 1) + j] : 1.0f;
    float* base = &lfTab[(size_t)b * NCLS * Sq + s];
    base[0] = cv * LOG2E;  // query-row class
#pragma unroll
    for (int c = 1; c < NCLS; ++c)
      base[c * Sq] = (inp && j == c - 1) ? LOG2E : 0.0f;
  }
}

// ---------------------------------------------------------------------------
// fp16 MFMA GEMM (r6/r11-proven config): C = A * B^T + bias.
//   128x128x64 tile, 4 waves 2x2, 16x16x32 MFMA.
//   Register-prefetch pipeline + XOR-swizzled 32 KB LDS, plain __syncthreads.
// MODE 0: Cp[m*N+n] = acc + bias (fp32)
// MODE 1: n<1024 -> q fp16 scaled 0.125*log2e; n<2048 -> k fp16; else vt fp16^T
// ---------------------------------------------------------------------------
template <int MODE>
__global__ __launch_bounds__(256) void gemm_f16(
    const f16* __restrict__ A, const f16* __restrict__ Bh,
    const float* __restrict__ bias, float* __restrict__ Cp,
    int M, int N, int Kd,
    f16* __restrict__ qo, f16* __restrict__ ko, f16* __restrict__ vto) {
  __shared__ __align__(16) f16 Ash[128 * 64];
  __shared__ __align__(16) f16 Bsh[128 * 64];

  const int tid = threadIdx.x;
  const int lane = tid & 63, w = tid >> 6;
  const int wm = w >> 1, wn = w & 1;
  const int q16 = lane & 15, quad = lane >> 4;
  const int m_blk = blockIdx.y * 128, n_blk = blockIdx.x * 128;

  fx4 acc[4][4];
#pragma unroll
  for (int mt = 0; mt < 4; ++mt)
#pragma unroll
    for (int nt = 0; nt < 4; ++nt)
#pragma unroll
      for (int r = 0; r < 4; ++r) acc[mt][nt][r] = 0.f;

  const int sr = tid >> 2, sc = (tid & 3) * 16;

  // register-prefetch buffers: [row-half][16B chunk]
  fh8 pa[2][2], pb[2][2];
  const f16* ga0 = &A[(size_t)(m_blk + sr) * Kd + sc];
  const f16* gb0 = &Bh[(size_t)(n_blk + sr) * Kd + sc];

#pragma unroll
  for (int h = 0; h < 2; ++h) {
    const f16* ga = ga0 + (size_t)h * 64 * Kd;
    pa[h][0] = *(const fh8*)&ga[0];
    pa[h][1] = *(const fh8*)&ga[8];
    const f16* gb = gb0 + (size_t)h * 64 * Kd;
    pb[h][0] = *(const fh8*)&gb[0];
    pb[h][1] = *(const fh8*)&gb[8];
  }

  for (int k0 = 0; k0 < Kd; k0 += 64) {
    __syncthreads();  // prior iteration's LDS frag reads complete
#pragma unroll
    for (int h = 0; h < 2; ++h) {
      const int r = sr + h * 64;
      *(fh8*)&Ash[SWZ(r, sc)]     = pa[h][0];
      *(fh8*)&Ash[SWZ(r, sc + 8)] = pa[h][1];
      *(fh8*)&Bsh[SWZ(r, sc)]     = pb[h][0];
      *(fh8*)&Bsh[SWZ(r, sc + 8)] = pb[h][1];
    }
    if (k0 + 64 < Kd) {  // issue next K-step loads; in flight during MFMA
      const int kn = k0 + 64;
#pragma unroll
      for (int h = 0; h < 2; ++h) {
        const f16* ga = ga0 + (size_t)h * 64 * Kd + kn;
        pa[h][0] = *(const fh8*)&ga[0];
        pa[h][1] = *(const fh8*)&ga[8];
        const f16* gb = gb0 + (size_t)h * 64 * Kd + kn;
        pb[h][0] = *(const fh8*)&gb[0];
        pb[h][1] = *(const fh8*)&gb[8];
      }
    }
    __syncthreads();

#pragma unroll
    for (int ks = 0; ks < 2; ++ks) {
      fh8 af[4], bfr[4];
#pragma unroll
      for (int mt = 0; mt < 4; ++mt)
        af[mt] = *(const fh8*)&Ash[SWZ(wm * 64 + mt * 16 + q16, ks * 32 + quad * 8)];
#pragma unroll
      for (int nt = 0; nt < 4; ++nt)
        bfr[nt] = *(const fh8*)&Bsh[SWZ(wn * 64 + nt * 16 + q16, ks * 32 + quad * 8)];
#pragma unroll
      for (int nt = 0; nt < 4; ++nt)
#pragma unroll
        for (int mt = 0; mt < 4; ++mt)
          acc[mt][nt] = __builtin_amdgcn_mfma_f32_16x16x32_f16(af[mt], bfr[nt], acc[mt][nt], 0, 0, 0);
    }
  }

  float bsv[4];
#pragma unroll
  for (int nt = 0; nt < 4; ++nt) bsv[nt] = bias[n_blk + wn * 64 + nt * 16 + q16];

  if (MODE == 0) {
#pragma unroll
    for (int mt = 0; mt < 4; ++mt)
#pragma unroll
      for (int r = 0; r < 4; ++r) {
        int row = m_blk + wm * 64 + mt * 16 + quad * 4 + r;
#pragma unroll
        for (int nt = 0; nt < 4; ++nt) {
          int col = n_blk + wn * 64 + nt * 16 + q16;
          Cp[(size_t)row * N + col] = acc[mt][nt][r] + bsv[nt];
        }
      }
  } else {
    const int n0 = n_blk + wn * 64;  // 64-aligned -> which/hd wave-uniform
    const int which = n0 >> 10;
    const int hd = (n0 & 1023) >> 6;
    const float scale = (which == 0) ? 0.125f * LOG2E : 1.0f;
#pragma unroll
    for (int mt = 0; mt < 4; ++mt)
#pragma unroll
      for (int r = 0; r < 4; ++r) {
        int m = m_blk + wm * 64 + mt * 16 + quad * 4 + r;
        int b = m >> 11, s = m & (Sq - 1);
#pragma unroll
        for (int nt = 0; nt < 4; ++nt) {
          int d = nt * 16 + q16;
          float x = (acc[mt][nt][r] + bsv[nt]) * scale;
          if (which == 2) {  // V transposed: (B,H,DH,S)
            vto[(((size_t)(b * Hh + hd)) * DHd + d) * Sq + s] = (f16)x;
          } else {
            f16* dst = (which == 0) ? qo : ko;
            dst[(((size_t)(b * Hh + hd)) * Sq + s) * DHd + d] = (f16)x;
          }
        }
      }
  }
}

// ---------------------------------------------------------------------------
// Flash attention v10: v6 structure (r11-proven) + in-register mask for
// non-query waves. For rows with rq>=0 the mask row is an interval
// indicator: lf = LOG2E iff col in [bnd[b][rq], bnd[b][rq+1]) (empty for
// rq==8). qwave = __any(rq<0) is wave-uniform and loop-invariant; fast waves
// (~90%) do ONE unsigned compare per element instead of a per-lane lfTab
// gather — removing the 2x ~250-cycle serial load chain from every tile.
// Query waves keep the exact lfTab path (identical values).
// ---------------------------------------------------------------------------
__global__ __launch_bounds__(256, 2) void attn_v10(
    const f16* __restrict__ Qf, const f16* __restrict__ Kf,
    const f16* __restrict__ Vt, const int* __restrict__ pidr,
    const float* __restrict__ lfTab, const int* __restrict__ bnd,
    f16* __restrict__ attf) {
  // XCD-aware decode: 1024 blocks = 8 XCDs x 128; orig id groups qb fastest.
  const int lin = blockIdx.x;
  const int orig = (lin & 7) * 128 + (lin >> 3);
  const int qb = orig & 15, hd = (orig >> 4) & 15, b = orig >> 8;
  const int bh = b * Hh + hd;
  const int tid = threadIdx.x;
  const int lane = tid & 63, w = tid >> 6;
  const int l31 = lane & 31, hi = lane >> 5;

  __shared__ __align__(16) f16 Ks[2][64 * 64];
  __shared__ __align__(16) f16 Vs[2][64 * 64];

  const size_t qkbase = (size_t)bh * Sq * DHd;   // (b,h,s,d)
  const size_t vtbase = (size_t)bh * DHd * Sq;   // (b,h,d,s)
  const int qrow = qb * 128 + w * 32 + l31;

  fh8 qf[4];
  {
    const f16* qp = &Qf[qkbase + (size_t)qrow * DHd + hi * 8];
#pragma unroll
    for (int ds = 0; ds < 4; ++ds) qf[ds] = *(const fh8*)&qp[ds * 16];
  }

  const int rq = pidr[b * Sq + qrow];
  const float* lfrow = &lfTab[((size_t)(b * NCLS + (rq + 1))) * Sq + 4 * hi];

  // fast-path interval for non-query waves
  const bool qwave = __any(rq < 0);
  int lob = 0;
  unsigned span = 0;
  if (!qwave) {  // all lanes have rq in [0, 8]
    lob = bnd[b * Kb + rq];
    int hib = (rq < Kb - 1) ? bnd[b * Kb + rq + 1] : lob;
    span = (unsigned)(hib - lob);
  }

  fh8 onesf;
#pragma unroll
  for (int j = 0; j < 8; ++j) onesf[j] = (l31 == 0) ? (f16)1.0f : (f16)0.0f;

  fx16 o_acc[2], lacc;
#pragma unroll
  for (int r = 0; r < 16; ++r) { o_acc[0][r] = 0.f; o_acc[1][r] = 0.f; lacc[r] = 0.f; }

  const int sr = tid >> 2, sc = (tid & 3) * 16;
  const int NT = Sq / 64;

  fh8 kc0, kc1, vc0, vc1;
  {
    const f16* gk = &Kf[qkbase + (size_t)sr * DHd + sc];
    kc0 = *(const fh8*)&gk[0]; kc1 = *(const fh8*)&gk[8];
    const f16* gv = &Vt[vtbase + (size_t)sr * Sq + sc];
    vc0 = *(const fh8*)&gv[0]; vc1 = *(const fh8*)&gv[8];
  }
  *(fh8*)&Ks[0][SWZ(sr, sc)]     = kc0;
  *(fh8*)&Ks[0][SWZ(sr, sc + 8)] = kc1;
  *(fh8*)&Vs[0][SWZ(sr, sc)]     = vc0;
  *(fh8*)&Vs[0][SWZ(sr, sc + 8)] = vc1;
  {
    const f16* gk = &Kf[qkbase + (size_t)(64 + sr) * DHd + sc];
    kc0 = *(const fh8*)&gk[0]; kc1 = *(const fh8*)&gk[8];
    const f16* gv = &Vt[vtbase + (size_t)sr * Sq + 64 + sc];
    vc0 = *(const fh8*)&gv[0]; vc1 = *(const fh8*)&gv[8];
  }
  __syncthreads();

  fx16 sacc0, sacc1;

  for (int kt = 0; kt < NT; ++kt) {
    const int c = kt & 1;

    // sacc0 C-init: fast compare path or lfTab gather
    if (!qwave) {
      const int cb = kt * 64 + 4 * hi - lob;
#pragma unroll
      for (int g = 0; g < 4; ++g)
#pragma unroll
        for (int j = 0; j < 4; ++j)
          sacc0[4 * g + j] = ((unsigned)(cb + 8 * g + j) < span) ? LOG2E : 0.0f;
    } else {
      const float* lp = &lfrow[kt * 64];
#pragma unroll
      for (int g = 0; g < 4; ++g) {
        float4 a = *(const float4*)&lp[8 * g];
        sacc0[4 * g + 0] = a.x; sacc0[4 * g + 1] = a.y;
        sacc0[4 * g + 2] = a.z; sacc0[4 * g + 3] = a.w;
      }
    }

    if (kt + 1 < NT) {
      *(fh8*)&Ks[c ^ 1][SWZ(sr, sc)]     = kc0;
      *(fh8*)&Ks[c ^ 1][SWZ(sr, sc + 8)] = kc1;
      *(fh8*)&Vs[c ^ 1][SWZ(sr, sc)]     = vc0;
      *(fh8*)&Vs[c ^ 1][SWZ(sr, sc + 8)] = vc1;
      if (kt + 2 < NT) {
        const f16* gk = &Kf[qkbase + (size_t)((kt + 2) * 64 + sr) * DHd + sc];
        kc0 = *(const fh8*)&gk[0]; kc1 = *(const fh8*)&gk[8];
        const f16* gv = &Vt[vtbase + (size_t)sr * Sq + (kt + 2) * 64 + sc];
        vc0 = *(const fh8*)&gv[0]; vc1 = *(const fh8*)&gv[8];
      }
    }

    auto half = [&](fx16& sacc, int s, bool preload_next) {
      fh8 kfr[4];
#pragma unroll
      for (int ds = 0; ds < 4; ++ds)
        kfr[ds] = *(const fh8*)&Ks[c][SWZ(s * 32 + l31, ds * 16 + hi * 8)];
      __builtin_amdgcn_s_setprio(1);
#pragma unroll
      for (int ds = 0; ds < 4; ++ds)
        sacc = __builtin_amdgcn_mfma_f32_32x32x16_f16(kfr[ds], qf[ds], sacc, 0, 0, 0);
      __builtin_amdgcn_s_setprio(0);

      if (preload_next) {  // sacc1 C-init
        if (!qwave) {
          const int cb = kt * 64 + 32 + 4 * hi - lob;
#pragma unroll
          for (int g = 0; g < 4; ++g)
#pragma unroll
            for (int j = 0; j < 4; ++j)
              sacc1[4 * g + j] = ((unsigned)(cb + 8 * g + j) < span) ? LOG2E : 0.0f;
        } else {
          const float* lp = &lfrow[kt * 64 + 32];
#pragma unroll
          for (int g = 0; g < 4; ++g) {
            float4 a = *(const float4*)&lp[8 * g];
            sacc1[4 * g + 0] = a.x; sacc1[4 * g + 1] = a.y;
            sacc1[4 * g + 2] = a.z; sacc1[4 * g + 3] = a.w;
          }
        }
      }

      int pk[8];
#pragma unroll
      for (int i = 0; i < 8; ++i) {
        fh2 h;
        h[0] = (f16)fexp2(sacc[2 * i]);
        h[1] = (f16)fexp2(sacc[2 * i + 1]);
        pk[i] = __builtin_bit_cast(int, h);
      }

      fh8 vfr[2][2];
#pragma unroll
      for (int dt = 0; dt < 2; ++dt)
#pragma unroll
        for (int kb = 0; kb < 2; ++kb)
          vfr[dt][kb] = *(const fh8*)&Vs[c][SWZ(dt * 32 + l31, s * 32 + kb * 16 + hi * 8)];

      __builtin_amdgcn_s_setprio(1);
#pragma unroll
      for (int kb = 0; kb < 2; ++kb) {
        int a01 = pk[4 * kb + 0], a23 = pk[4 * kb + 1];
        int a45 = pk[4 * kb + 2], a67 = pk[4 * kb + 3];
        i4 t;
#if __has_builtin(__builtin_amdgcn_permlane32_swap)
        auto s0 = __builtin_amdgcn_permlane32_swap(a01, a45, false, false);
        auto s1 = __builtin_amdgcn_permlane32_swap(a23, a67, false, false);
        t[0] = s0[0]; t[1] = s1[0]; t[2] = s0[1]; t[3] = s1[1];
#else
        int x01 = __shfl_xor(a01, 32), x23 = __shfl_xor(a23, 32);
        int x45 = __shfl_xor(a45, 32), x67 = __shfl_xor(a67, 32);
        t[0] = hi ? x45 : a01; t[1] = hi ? x67 : a23;
        t[2] = hi ? a45 : x01; t[3] = hi ? a67 : x23;
#endif
        fh8 pf = __builtin_bit_cast(fh8, t);
        lacc = __builtin_amdgcn_mfma_f32_32x32x16_f16(onesf, pf, lacc, 0, 0, 0);
        o_acc[0] = __builtin_amdgcn_mfma_f32_32x32x16_f16(vfr[0][kb], pf, o_acc[0], 0, 0, 0);
        o_acc[1] = __builtin_amdgcn_mfma_f32_32x32x16_f16(vfr[1][kb], pf, o_acc[1], 0, 0, 0);
      }
      __builtin_amdgcn_s_setprio(0);
    };

    half(sacc0, 0, true);
    half(sacc1, 1, false);

    if (kt + 1 < NT) __syncthreads();
  }

  float l = __shfl(lacc[0], l31);
  float inv = 1.0f / l;
  size_t obase = ((size_t)(b * Sq + qrow)) * Eq + hd * 64 + 4 * hi;
#pragma unroll
  for (int dt = 0; dt < 2; ++dt)
#pragma unroll
    for (int g = 0; g < 4; ++g) {
      fh4 o4;
#pragma unroll
      for (int j = 0; j < 4; ++j) o4[j] = (f16)(o_acc[dt][4 * g + j] * inv);
      *(fh4*)&attf[obase + dt * 32 + 8 * g] = o4;
    }
}

// ---------------------------------------------------------------------------
extern "C" void kernel_launch(void* const* d_in, const int* in_sizes, int n_in,
                              void* d_out, int out_size, void* d_ws, size_t ws_size,
                              hipStream_t stream) {
  const float* hs = (const float*)d_in[0];
  const float* rel = (const float*)d_in[1];
  const int* bnd = (const int*)d_in[2];
  const float* wi = (const float*)d_in[3];
  const float* bi = (const float*)d_in[4];
  const float* wo = (const float*)d_in[5];
  const float* bo = (const float*)d_in[6];
  float* out = (float*)d_out;

  const size_t NQ = (size_t)Bsz * Hh * Sq * DHd;  // 8,388,608 (== B*S*E)
  char* p = (char*)d_ws;
  f16* qf = (f16*)p;   p += NQ * 2;
  f16* kf = (f16*)p;   p += NQ * 2;
  f16* vt = (f16*)p;   p += NQ * 2;
  f16* hsf = (f16*)p;  p += NQ * 2;
  f16* attf = (f16*)p; p += NQ * 2;
  f16* wif = (f16*)p;  p += (size_t)3 * Eq * Eq * 2;
  f16* wof = (f16*)p;  p += (size_t)Eq * Eq * 2;
  int* pidr = (int*)p; p += Bsz * Sq * 4;
  float* lfTab = (float*)p;  // Bsz*NCLS*Sq*4 = 327KB
  // total ~93 MB < proven 134 MB footprint

  hipLaunchKernelGGL(prep, dim3(6176), dim3(256), 0, stream,
                     hs, hsf, wi, wif, wo, wof, bnd, rel, pidr, lfTab);
  hipLaunchKernelGGL((gemm_f16<1>), dim3(24, 64), dim3(256), 0, stream,
                     hsf, wif, bi, (float*)nullptr, Bsz * Sq, 3 * Eq, Eq,
                     qf, kf, vt);
  hipLaunchKernelGGL(attn_v10, dim3(16 * 16 * 4), dim3(256), 0, stream,
                     qf, kf, vt, pidr, lfTab, bnd, attf);
  hipLaunchKernelGGL((gemm_f16<0>), dim3(8, 64), dim3(256), 0, stream,
                     attf, wof, bo, out, Bsz * Sq, Eq, Eq,
                     nullptr, nullptr, nullptr);
}

// Round 15
// 300.173 us; speedup vs baseline: 1.0437x; 1.0437x over previous
//
#include <hip/hip_runtime.h>
#include <math.h>

#define Bsz 4
#define Sq  2048
#define Eq  1024
#define Hh  16
#define DHd 64
#define Kb  9
#define LOG2E 1.44269504088896340736f
#define NCLS 10  // row classes: query(-1) + pids 0..8

typedef _Float16 f16;
typedef __attribute__((ext_vector_type(8))) _Float16 fh8;   // MFMA A/B frag (4 VGPRs)
typedef __attribute__((ext_vector_type(4))) _Float16 fh4;
typedef __attribute__((ext_vector_type(2))) _Float16 fh2;
typedef __attribute__((ext_vector_type(4))) float fx4;      // 16x16 C/D frag
typedef __attribute__((ext_vector_type(16))) float fx16;    // 32x32 C/D frag
typedef __attribute__((ext_vector_type(4))) int i4;

// LDS swizzle: 64-half rows (128 B) -> XOR row into 16B-chunk index.
#define SWZ(r, c) ((r) * 64 + ((c) ^ (((r) & 7) << 3)))

static __device__ __forceinline__ float fexp2(float x) {
#if __has_builtin(__builtin_amdgcn_exp2f)
  return __builtin_amdgcn_exp2f(x);   // raw v_exp_f32
#else
  return __expf(x * 0.6931471805599453f);
#endif
}

// lgkm-only barrier (T4), UNFENCED: completes this wave's LDS ops, then raw
// s_barrier — without __syncthreads' vmcnt(0) drain, so prefetch global
// loads stay in flight across the barrier. The "memory" clobber orders all
// memory ops (ds_read/ds_write/global_load) across the asm; MFMA operands
// come from compiler-tracked ds_reads, so the compiler inserts its own
// lgkmcnt waits before use (no sched_barrier fences needed — r12's fenced
// version regressed per the m141 order-pinning failure mode).
static __device__ __forceinline__ void barrier_lgkm() {
  asm volatile("s_waitcnt lgkmcnt(0)" ::: "memory");
  __builtin_amdgcn_s_barrier();
}

// ---------------------------------------------------------------------------
// prep: fused pid/lfTab build + fp32->fp16 casts of hs, wi, wo (one launch).
// ---------------------------------------------------------------------------
__global__ __launch_bounds__(256) void prep(
    const float* __restrict__ hs, f16* __restrict__ hsf,
    const float* __restrict__ wi, f16* __restrict__ wif,
    const float* __restrict__ wo, f16* __restrict__ wof,
    const int* __restrict__ bnd, const float* __restrict__ rel,
    int* __restrict__ pidr, float* __restrict__ lfTab) {
  const int bid = blockIdx.x;
  if (bid < 6144) {
    const float* src;
    f16* dst;
    int off;
    if (bid < 4096)      { src = hs; dst = hsf; off = bid; }
    else if (bid < 5632) { src = wi; dst = wif; off = bid - 4096; }
    else                 { src = wo; dst = wof; off = bid - 5632; }
    int i = (off * 256 + threadIdx.x) * 8;
    float4 a = *(const float4*)&src[i];
    float4 b = *(const float4*)&src[i + 4];
    fh8 o;
    o[0] = (f16)a.x; o[1] = (f16)a.y; o[2] = (f16)a.z; o[3] = (f16)a.w;
    o[4] = (f16)b.x; o[5] = (f16)b.y; o[6] = (f16)b.z; o[7] = (f16)b.w;
    *(fh8*)&dst[i] = o;
  } else {
    int idx = (bid - 6144) * 256 + threadIdx.x;
    if (idx >= Bsz * Sq) return;
    int b = idx >> 11;
    int s = idx & (Sq - 1);
    int j = -1;
#pragma unroll
    for (int t = 0; t < Kb; ++t) {
      if (bnd[b * Kb + t] <= s) j = t;
    }
    pidr[idx] = j;
    bool inp = (j >= 0 && j < Kb - 1);
    float cv = inp ? rel[b * (Kb - 1) + j] : 1.0f;
    float* base = &lfTab[(size_t)b * NCLS * Sq + s];
    base[0] = cv * LOG2E;  // query-row class
#pragma unroll
    for (int c = 1; c < NCLS; ++c)
      base[c * Sq] = (inp && j == c - 1) ? LOG2E : 0.0f;
  }
}

// ---------------------------------------------------------------------------
// fp16 MFMA GEMM (r6/r11 structure + unfenced lgkm-only K-loop barriers):
//   C = A * B^T + bias. 128x128x64 tile, 4 waves 2x2, 16x16x32 MFMA.
//   Register-prefetch pipeline + XOR-swizzled 32 KB LDS. With lgkm-only
//   barriers, the next-K-step global loads genuinely stay in flight through
//   the MFMA phase (plain __syncthreads drained them at every step).
// MODE 0: Cp[m*N+n] = acc + bias (fp32)
// MODE 1: n<1024 -> q fp16 scaled 0.125*log2e; n<2048 -> k fp16; else vt fp16^T
// ---------------------------------------------------------------------------
template <int MODE>
__global__ __launch_bounds__(256) void gemm_f16(
    const f16* __restrict__ A, const f16* __restrict__ Bh,
    const float* __restrict__ bias, float* __restrict__ Cp,
    int M, int N, int Kd,
    f16* __restrict__ qo, f16* __restrict__ ko, f16* __restrict__ vto) {
  __shared__ __align__(16) f16 Ash[128 * 64];
  __shared__ __align__(16) f16 Bsh[128 * 64];

  const int tid = threadIdx.x;
  const int lane = tid & 63, w = tid >> 6;
  const int wm = w >> 1, wn = w & 1;
  const int q16 = lane & 15, quad = lane >> 4;
  const int m_blk = blockIdx.y * 128, n_blk = blockIdx.x * 128;

  fx4 acc[4][4];
#pragma unroll
  for (int mt = 0; mt < 4; ++mt)
#pragma unroll
    for (int nt = 0; nt < 4; ++nt)
#pragma unroll
      for (int r = 0; r < 4; ++r) acc[mt][nt][r] = 0.f;

  const int sr = tid >> 2, sc = (tid & 3) * 16;

  // register-prefetch buffers: [row-half][16B chunk]
  fh8 pa[2][2], pb[2][2];
  const f16* ga0 = &A[(size_t)(m_blk + sr) * Kd + sc];
  const f16* gb0 = &Bh[(size_t)(n_blk + sr) * Kd + sc];

#pragma unroll
  for (int h = 0; h < 2; ++h) {
    const f16* ga = ga0 + (size_t)h * 64 * Kd;
    pa[h][0] = *(const fh8*)&ga[0];
    pa[h][1] = *(const fh8*)&ga[8];
    const f16* gb = gb0 + (size_t)h * 64 * Kd;
    pb[h][0] = *(const fh8*)&gb[0];
    pb[h][1] = *(const fh8*)&gb[8];
  }

  for (int k0 = 0; k0 < Kd; k0 += 64) {
    barrier_lgkm();  // prior iteration's LDS frag reads complete (lgkm only)
#pragma unroll
    for (int h = 0; h < 2; ++h) {
      const int r = sr + h * 64;
      *(fh8*)&Ash[SWZ(r, sc)]     = pa[h][0];
      *(fh8*)&Ash[SWZ(r, sc + 8)] = pa[h][1];
      *(fh8*)&Bsh[SWZ(r, sc)]     = pb[h][0];
      *(fh8*)&Bsh[SWZ(r, sc + 8)] = pb[h][1];
    }
    if (k0 + 64 < Kd) {  // issue next K-step loads; stay in flight thru MFMA
      const int kn = k0 + 64;
#pragma unroll
      for (int h = 0; h < 2; ++h) {
        const f16* ga = ga0 + (size_t)h * 64 * Kd + kn;
        pa[h][0] = *(const fh8*)&ga[0];
        pa[h][1] = *(const fh8*)&ga[8];
        const f16* gb = gb0 + (size_t)h * 64 * Kd + kn;
        pb[h][0] = *(const fh8*)&gb[0];
        pb[h][1] = *(const fh8*)&gb[8];
      }
    }
    barrier_lgkm();  // ds_writes visible; prefetch loads NOT drained

#pragma unroll
    for (int ks = 0; ks < 2; ++ks) {
      fh8 af[4], bfr[4];
#pragma unroll
      for (int mt = 0; mt < 4; ++mt)
        af[mt] = *(const fh8*)&Ash[SWZ(wm * 64 + mt * 16 + q16, ks * 32 + quad * 8)];
#pragma unroll
      for (int nt = 0; nt < 4; ++nt)
        bfr[nt] = *(const fh8*)&Bsh[SWZ(wn * 64 + nt * 16 + q16, ks * 32 + quad * 8)];
#pragma unroll
      for (int nt = 0; nt < 4; ++nt)
#pragma unroll
        for (int mt = 0; mt < 4; ++mt)
          acc[mt][nt] = __builtin_amdgcn_mfma_f32_16x16x32_f16(af[mt], bfr[nt], acc[mt][nt], 0, 0, 0);
    }
  }

  float bsv[4];
#pragma unroll
  for (int nt = 0; nt < 4; ++nt) bsv[nt] = bias[n_blk + wn * 64 + nt * 16 + q16];

  if (MODE == 0) {
#pragma unroll
    for (int mt = 0; mt < 4; ++mt)
#pragma unroll
      for (int r = 0; r < 4; ++r) {
        int row = m_blk + wm * 64 + mt * 16 + quad * 4 + r;
#pragma unroll
        for (int nt = 0; nt < 4; ++nt) {
          int col = n_blk + wn * 64 + nt * 16 + q16;
          Cp[(size_t)row * N + col] = acc[mt][nt][r] + bsv[nt];
        }
      }
  } else {
    const int n0 = n_blk + wn * 64;  // 64-aligned -> which/hd wave-uniform
    const int which = n0 >> 10;
    const int hd = (n0 & 1023) >> 6;
    const float scale = (which == 0) ? 0.125f * LOG2E : 1.0f;
#pragma unroll
    for (int mt = 0; mt < 4; ++mt)
#pragma unroll
      for (int r = 0; r < 4; ++r) {
        int m = m_blk + wm * 64 + mt * 16 + quad * 4 + r;
        int b = m >> 11, s = m & (Sq - 1);
#pragma unroll
        for (int nt = 0; nt < 4; ++nt) {
          int d = nt * 16 + q16;
          float x = (acc[mt][nt][r] + bsv[nt]) * scale;
          if (which == 2) {  // V transposed: (B,H,DH,S)
            vto[(((size_t)(b * Hh + hd)) * DHd + d) * Sq + s] = (f16)x;
          } else {
            f16* dst = (which == 0) ? qo : ko;
            dst[(((size_t)(b * Hh + hd)) * Sq + s) * DHd + d] = (f16)x;
          }
        }
      }
  }
}

// ---------------------------------------------------------------------------
// Flash attention v6 (r11-proven, 103.4 us — byte-identical): swapped-QK
// 32x32 MFMA, register-resident P, raw v_exp_f32, mask as MFMA C-init,
// ones-row MFMA row-sum, double-buffered LDS, XCD-swizzled 1D grid, setprio.
// ---------------------------------------------------------------------------
__global__ __launch_bounds__(256, 2) void attn_v6(
    const f16* __restrict__ Qf, const f16* __restrict__ Kf,
    const f16* __restrict__ Vt, const int* __restrict__ pidr,
    const float* __restrict__ lfTab, f16* __restrict__ attf) {
  // XCD-aware decode: 1024 blocks = 8 XCDs x 128; orig id groups qb fastest.
  const int lin = blockIdx.x;
  const int orig = (lin & 7) * 128 + (lin >> 3);
  const int qb = orig & 15, hd = (orig >> 4) & 15, b = orig >> 8;
  const int bh = b * Hh + hd;
  const int tid = threadIdx.x;
  const int lane = tid & 63, w = tid >> 6;
  const int l31 = lane & 31, hi = lane >> 5;

  __shared__ __align__(16) f16 Ks[2][64 * 64];
  __shared__ __align__(16) f16 Vs[2][64 * 64];

  const size_t qkbase = (size_t)bh * Sq * DHd;   // (b,h,s,d)
  const size_t vtbase = (size_t)bh * DHd * Sq;   // (b,h,d,s)
  const int qrow = qb * 128 + w * 32 + l31;

  fh8 qf[4];
  {
    const f16* qp = &Qf[qkbase + (size_t)qrow * DHd + hi * 8];
#pragma unroll
    for (int ds = 0; ds < 4; ++ds) qf[ds] = *(const fh8*)&qp[ds * 16];
  }

  const int rq = pidr[b * Sq + qrow];
  const float* lfrow = &lfTab[((size_t)(b * NCLS + (rq + 1))) * Sq + 4 * hi];

  fh8 onesf;
#pragma unroll
  for (int j = 0; j < 8; ++j) onesf[j] = (l31 == 0) ? (f16)1.0f : (f16)0.0f;

  fx16 o_acc[2], lacc;
#pragma unroll
  for (int r = 0; r < 16; ++r) { o_acc[0][r] = 0.f; o_acc[1][r] = 0.f; lacc[r] = 0.f; }

  const int sr = tid >> 2, sc = (tid & 3) * 16;
  const int NT = Sq / 64;

  fh8 kc0, kc1, vc0, vc1;
  {
    const f16* gk = &Kf[qkbase + (size_t)sr * DHd + sc];
    kc0 = *(const fh8*)&gk[0]; kc1 = *(const fh8*)&gk[8];
    const f16* gv = &Vt[vtbase + (size_t)sr * Sq + sc];
    vc0 = *(const fh8*)&gv[0]; vc1 = *(const fh8*)&gv[8];
  }
  *(fh8*)&Ks[0][SWZ(sr, sc)]     = kc0;
  *(fh8*)&Ks[0][SWZ(sr, sc + 8)] = kc1;
  *(fh8*)&Vs[0][SWZ(sr, sc)]     = vc0;
  *(fh8*)&Vs[0][SWZ(sr, sc + 8)] = vc1;
  {
    const f16* gk = &Kf[qkbase + (size_t)(64 + sr) * DHd + sc];
    kc0 = *(const fh8*)&gk[0]; kc1 = *(const fh8*)&gk[8];
    const f16* gv = &Vt[vtbase + (size_t)sr * Sq + 64 + sc];
    vc0 = *(const fh8*)&gv[0]; vc1 = *(const fh8*)&gv[8];
  }
  __syncthreads();

  fx16 sacc0, sacc1;

  for (int kt = 0; kt < NT; ++kt) {
    const int c = kt & 1;

    {
      const float* lp = &lfrow[kt * 64];
#pragma unroll
      for (int g = 0; g < 4; ++g) {
        float4 a = *(const float4*)&lp[8 * g];
        sacc0[4 * g + 0] = a.x; sacc0[4 * g + 1] = a.y;
        sacc0[4 * g + 2] = a.z; sacc0[4 * g + 3] = a.w;
      }
    }

    if (kt + 1 < NT) {
      *(fh8*)&Ks[c ^ 1][SWZ(sr, sc)]     = kc0;
      *(fh8*)&Ks[c ^ 1][SWZ(sr, sc + 8)] = kc1;
      *(fh8*)&Vs[c ^ 1][SWZ(sr, sc)]     = vc0;
      *(fh8*)&Vs[c ^ 1][SWZ(sr, sc + 8)] = vc1;
      if (kt + 2 < NT) {
        const f16* gk = &Kf[qkbase + (size_t)((kt + 2) * 64 + sr) * DHd + sc];
        kc0 = *(const fh8*)&gk[0]; kc1 = *(const fh8*)&gk[8];
        const f16* gv = &Vt[vtbase + (size_t)sr * Sq + (kt + 2) * 64 + sc];
        vc0 = *(const fh8*)&gv[0]; vc1 = *(const fh8*)&gv[8];
      }
    }

    auto half = [&](fx16& sacc, int s, bool preload_next) {
      fh8 kfr[4];
#pragma unroll
      for (int ds = 0; ds < 4; ++ds)
        kfr[ds] = *(const fh8*)&Ks[c][SWZ(s * 32 + l31, ds * 16 + hi * 8)];
      __builtin_amdgcn_s_setprio(1);
#pragma unroll
      for (int ds = 0; ds < 4; ++ds)
        sacc = __builtin_amdgcn_mfma_f32_32x32x16_f16(kfr[ds], qf[ds], sacc, 0, 0, 0);
      __builtin_amdgcn_s_setprio(0);

      if (preload_next) {
        const float* lp = &lfrow[kt * 64 + 32];
#pragma unroll
        for (int g = 0; g < 4; ++g) {
          float4 a = *(const float4*)&lp[8 * g];
          sacc1[4 * g + 0] = a.x; sacc1[4 * g + 1] = a.y;
          sacc1[4 * g + 2] = a.z; sacc1[4 * g + 3] = a.w;
        }
      }

      int pk[8];
#pragma unroll
      for (int i = 0; i < 8; ++i) {
        fh2 h;
        h[0] = (f16)fexp2(sacc[2 * i]);
        h[1] = (f16)fexp2(sacc[2 * i + 1]);
        pk[i] = __builtin_bit_cast(int, h);
      }

      fh8 vfr[2][2];
#pragma unroll
      for (int dt = 0; dt < 2; ++dt)
#pragma unroll
        for (int kb = 0; kb < 2; ++kb)
          vfr[dt][kb] = *(const fh8*)&Vs[c][SWZ(dt * 32 + l31, s * 32 + kb * 16 + hi * 8)];

      __builtin_amdgcn_s_setprio(1);
#pragma unroll
      for (int kb = 0; kb < 2; ++kb) {
        int a01 = pk[4 * kb + 0], a23 = pk[4 * kb + 1];
        int a45 = pk[4 * kb + 2], a67 = pk[4 * kb + 3];
        i4 t;
#if __has_builtin(__builtin_amdgcn_permlane32_swap)
        auto s0 = __builtin_amdgcn_permlane32_swap(a01, a45, false, false);
        auto s1 = __builtin_amdgcn_permlane32_swap(a23, a67, false, false);
        t[0] = s0[0]; t[1] = s1[0]; t[2] = s0[1]; t[3] = s1[1];
#else
        int x01 = __shfl_xor(a01, 32), x23 = __shfl_xor(a23, 32);
        int x45 = __shfl_xor(a45, 32), x67 = __shfl_xor(a67, 32);
        t[0] = hi ? x45 : a01; t[1] = hi ? x67 : a23;
        t[2] = hi ? a45 : x01; t[3] = hi ? a67 : x23;
#endif
        fh8 pf = __builtin_bit_cast(fh8, t);
        lacc = __builtin_amdgcn_mfma_f32_32x32x16_f16(onesf, pf, lacc, 0, 0, 0);
        o_acc[0] = __builtin_amdgcn_mfma_f32_32x32x16_f16(vfr[0][kb], pf, o_acc[0], 0, 0, 0);
        o_acc[1] = __builtin_amdgcn_mfma_f32_32x32x16_f16(vfr[1][kb], pf, o_acc[1], 0, 0, 0);
      }
      __builtin_amdgcn_s_setprio(0);
    };

    half(sacc0, 0, true);
    half(sacc1, 1, false);

    if (kt + 1 < NT) __syncthreads();
  }

  float l = __shfl(lacc[0], l31);
  float inv = 1.0f / l;
  size_t obase = ((size_t)(b * Sq + qrow)) * Eq + hd * 64 + 4 * hi;
#pragma unroll
  for (int dt = 0; dt < 2; ++dt)
#pragma unroll
    for (int g = 0; g < 4; ++g) {
      fh4 o4;
#pragma unroll
      for (int j = 0; j < 4; ++j) o4[j] = (f16)(o_acc[dt][4 * g + j] * inv);
      *(fh4*)&attf[obase + dt * 32 + 8 * g] = o4;
    }
}

// ---------------------------------------------------------------------------
extern "C" void kernel_launch(void* const* d_in, const int* in_sizes, int n_in,
                              void* d_out, int out_size, void* d_ws, size_t ws_size,
                              hipStream_t stream) {
  const float* hs = (const float*)d_in[0];
  const float* rel = (const float*)d_in[1];
  const int* bnd = (const int*)d_in[2];
  const float* wi = (const float*)d_in[3];
  const float* bi = (const float*)d_in[4];
  const float* wo = (const float*)d_in[5];
  const float* bo = (const float*)d_in[6];
  float* out = (float*)d_out;

  const size_t NQ = (size_t)Bsz * Hh * Sq * DHd;  // 8,388,608 (== B*S*E)
  char* p = (char*)d_ws;
  f16* qf = (f16*)p;   p += NQ * 2;
  f16* kf = (f16*)p;   p += NQ * 2;
  f16* vt = (f16*)p;   p += NQ * 2;
  f16* hsf = (f16*)p;  p += NQ * 2;
  f16* attf = (f16*)p; p += NQ * 2;
  f16* wif = (f16*)p;  p += (size_t)3 * Eq * Eq * 2;
  f16* wof = (f16*)p;  p += (size_t)Eq * Eq * 2;
  int* pidr = (int*)p; p += Bsz * Sq * 4;
  float* lfTab = (float*)p;  // Bsz*NCLS*Sq*4 = 327KB
  // total ~93 MB < proven 134 MB footprint

  hipLaunchKernelGGL(prep, dim3(6176), dim3(256), 0, stream,
                     hs, hsf, wi, wif, wo, wof, bnd, rel, pidr, lfTab);
  hipLaunchKernelGGL((gemm_f16<1>), dim3(24, 64), dim3(256), 0, stream,
                     hsf, wif, bi, (float*)nullptr, Bsz * Sq, 3 * Eq, Eq,
                     qf, kf, vt);
  hipLaunchKernelGGL(attn_v6, dim3(16 * 16 * 4), dim3(256), 0, stream,
                     qf, kf, vt, pidr, lfTab, attf);
  hipLaunchKernelGGL((gemm_f16<0>), dim3(8, 64), dim3(256), 0, stream,
                     attf, wof, bo, out, Bsz * Sq, Eq, Eq,
                     nullptr, nullptr, nullptr);
}

// Round 16
// 297.024 us; speedup vs baseline: 1.0548x; 1.0106x over previous
//
#include <hip/hip_runtime.h>
#include <math.h>

#define Bsz 4
#define Sq  2048
#define Eq  1024
#define Hh  16
#define DHd 64
#define Kb  9
#define LOG2E 1.44269504088896340736f
#define NCLS 10  // row classes: query(-1) + pids 0..8

typedef _Float16 f16;
typedef __attribute__((ext_vector_type(8))) _Float16 fh8;   // MFMA A/B frag (4 VGPRs)
typedef __attribute__((ext_vector_type(4))) _Float16 fh4;
typedef __attribute__((ext_vector_type(2))) _Float16 fh2;
typedef __attribute__((ext_vector_type(4))) float fx4;      // 16x16 C/D frag
typedef __attribute__((ext_vector_type(16))) float fx16;    // 32x32 C/D frag
typedef __attribute__((ext_vector_type(4))) int i4;

// LDS swizzle: 64-half rows (128 B) -> XOR row into 16B-chunk index.
#define SWZ(r, c) ((r) * 64 + ((c) ^ (((r) & 7) << 3)))

static __device__ __forceinline__ float fexp2(float x) {
#if __has_builtin(__builtin_amdgcn_exp2f)
  return __builtin_amdgcn_exp2f(x);   // raw v_exp_f32
#else
  return __expf(x * 0.6931471805599453f);
#endif
}

// ---------------------------------------------------------------------------
// prep: fused pid/lfTab build + fp32->fp16 casts of hs, wi, wo (one launch).
// ---------------------------------------------------------------------------
__global__ __launch_bounds__(256) void prep(
    const float* __restrict__ hs, f16* __restrict__ hsf,
    const float* __restrict__ wi, f16* __restrict__ wif,
    const float* __restrict__ wo, f16* __restrict__ wof,
    const int* __restrict__ bnd, const float* __restrict__ rel,
    int* __restrict__ pidr, float* __restrict__ lfTab) {
  const int bid = blockIdx.x;
  if (bid < 6144) {
    const float* src;
    f16* dst;
    int off;
    if (bid < 4096)      { src = hs; dst = hsf; off = bid; }
    else if (bid < 5632) { src = wi; dst = wif; off = bid - 4096; }
    else                 { src = wo; dst = wof; off = bid - 5632; }
    int i = (off * 256 + threadIdx.x) * 8;
    float4 a = *(const float4*)&src[i];
    float4 b = *(const float4*)&src[i + 4];
    fh8 o;
    o[0] = (f16)a.x; o[1] = (f16)a.y; o[2] = (f16)a.z; o[3] = (f16)a.w;
    o[4] = (f16)b.x; o[5] = (f16)b.y; o[6] = (f16)b.z; o[7] = (f16)b.w;
    *(fh8*)&dst[i] = o;
  } else {
    int idx = (bid - 6144) * 256 + threadIdx.x;
    if (idx >= Bsz * Sq) return;
    int b = idx >> 11;
    int s = idx & (Sq - 1);
    int j = -1;
#pragma unroll
    for (int t = 0; t < Kb; ++t) {
      if (bnd[b * Kb + t] <= s) j = t;
    }
    pidr[idx] = j;
    bool inp = (j >= 0 && j < Kb - 1);
    float cv = inp ? rel[b * (Kb - 1) + j] : 1.0f;
    float* base = &lfTab[(size_t)b * NCLS * Sq + s];
    base[0] = cv * LOG2E;  // query-row class
#pragma unroll
    for (int c = 1; c < NCLS; ++c)
      base[c * Sq] = (inp && j == c - 1) ? LOG2E : 0.0f;
  }
}

// ---------------------------------------------------------------------------
// fp16 MFMA GEMM (r6/r11-proven config, __syncthreads restored):
//   C = A * B^T + bias. 128x128x64 tile, 4 waves 2x2, 16x16x32 MFMA.
//   Register-prefetch pipeline + XOR-swizzled 32 KB LDS.
// MODE 0: Cp[m*N+n] = acc + bias (fp32)
// MODE 1: n<1024 -> q fp16 scaled 0.125*log2e; n<2048 -> k fp16; else vt fp16^T
// ---------------------------------------------------------------------------
template <int MODE>
__global__ __launch_bounds__(256) void gemm_f16(
    const f16* __restrict__ A, const f16* __restrict__ Bh,
    const float* __restrict__ bias, float* __restrict__ Cp,
    int M, int N, int Kd,
    f16* __restrict__ qo, f16* __restrict__ ko, f16* __restrict__ vto) {
  __shared__ __align__(16) f16 Ash[128 * 64];
  __shared__ __align__(16) f16 Bsh[128 * 64];

  const int tid = threadIdx.x;
  const int lane = tid & 63, w = tid >> 6;
  const int wm = w >> 1, wn = w & 1;
  const int q16 = lane & 15, quad = lane >> 4;
  const int m_blk = blockIdx.y * 128, n_blk = blockIdx.x * 128;

  fx4 acc[4][4];
#pragma unroll
  for (int mt = 0; mt < 4; ++mt)
#pragma unroll
    for (int nt = 0; nt < 4; ++nt)
#pragma unroll
      for (int r = 0; r < 4; ++r) acc[mt][nt][r] = 0.f;

  const int sr = tid >> 2, sc = (tid & 3) * 16;

  // register-prefetch buffers: [row-half][16B chunk]
  fh8 pa[2][2], pb[2][2];
  const f16* ga0 = &A[(size_t)(m_blk + sr) * Kd + sc];
  const f16* gb0 = &Bh[(size_t)(n_blk + sr) * Kd + sc];

#pragma unroll
  for (int h = 0; h < 2; ++h) {
    const f16* ga = ga0 + (size_t)h * 64 * Kd;
    pa[h][0] = *(const fh8*)&ga[0];
    pa[h][1] = *(const fh8*)&ga[8];
    const f16* gb = gb0 + (size_t)h * 64 * Kd;
    pb[h][0] = *(const fh8*)&gb[0];
    pb[h][1] = *(const fh8*)&gb[8];
  }

  for (int k0 = 0; k0 < Kd; k0 += 64) {
    __syncthreads();  // prior iteration's LDS frag reads complete
#pragma unroll
    for (int h = 0; h < 2; ++h) {
      const int r = sr + h * 64;
      *(fh8*)&Ash[SWZ(r, sc)]     = pa[h][0];
      *(fh8*)&Ash[SWZ(r, sc + 8)] = pa[h][1];
      *(fh8*)&Bsh[SWZ(r, sc)]     = pb[h][0];
      *(fh8*)&Bsh[SWZ(r, sc + 8)] = pb[h][1];
    }
    if (k0 + 64 < Kd) {  // issue next K-step loads; in flight during MFMA
      const int kn = k0 + 64;
#pragma unroll
      for (int h = 0; h < 2; ++h) {
        const f16* ga = ga0 + (size_t)h * 64 * Kd + kn;
        pa[h][0] = *(const fh8*)&ga[0];
        pa[h][1] = *(const fh8*)&ga[8];
        const f16* gb = gb0 + (size_t)h * 64 * Kd + kn;
        pb[h][0] = *(const fh8*)&gb[0];
        pb[h][1] = *(const fh8*)&gb[8];
      }
    }
    __syncthreads();

#pragma unroll
    for (int ks = 0; ks < 2; ++ks) {
      fh8 af[4], bfr[4];
#pragma unroll
      for (int mt = 0; mt < 4; ++mt)
        af[mt] = *(const fh8*)&Ash[SWZ(wm * 64 + mt * 16 + q16, ks * 32 + quad * 8)];
#pragma unroll
      for (int nt = 0; nt < 4; ++nt)
        bfr[nt] = *(const fh8*)&Bsh[SWZ(wn * 64 + nt * 16 + q16, ks * 32 + quad * 8)];
#pragma unroll
      for (int nt = 0; nt < 4; ++nt)
#pragma unroll
        for (int mt = 0; mt < 4; ++mt)
          acc[mt][nt] = __builtin_amdgcn_mfma_f32_16x16x32_f16(af[mt], bfr[nt], acc[mt][nt], 0, 0, 0);
    }
  }

  float bsv[4];
#pragma unroll
  for (int nt = 0; nt < 4; ++nt) bsv[nt] = bias[n_blk + wn * 64 + nt * 16 + q16];

  if (MODE == 0) {
#pragma unroll
    for (int mt = 0; mt < 4; ++mt)
#pragma unroll
      for (int r = 0; r < 4; ++r) {
        int row = m_blk + wm * 64 + mt * 16 + quad * 4 + r;
#pragma unroll
        for (int nt = 0; nt < 4; ++nt) {
          int col = n_blk + wn * 64 + nt * 16 + q16;
          Cp[(size_t)row * N + col] = acc[mt][nt][r] + bsv[nt];
        }
      }
  } else {
    const int n0 = n_blk + wn * 64;  // 64-aligned -> which/hd wave-uniform
    const int which = n0 >> 10;
    const int hd = (n0 & 1023) >> 6;
    const float scale = (which == 0) ? 0.125f * LOG2E : 1.0f;
#pragma unroll
    for (int mt = 0; mt < 4; ++mt)
#pragma unroll
      for (int r = 0; r < 4; ++r) {
        int m = m_blk + wm * 64 + mt * 16 + quad * 4 + r;
        int b = m >> 11, s = m & (Sq - 1);
#pragma unroll
        for (int nt = 0; nt < 4; ++nt) {
          int d = nt * 16 + q16;
          float x = (acc[mt][nt][r] + bsv[nt]) * scale;
          if (which == 2) {  // V transposed: (B,H,DH,S)
            vto[(((size_t)(b * Hh + hd)) * DHd + d) * Sq + s] = (f16)x;
          } else {
            f16* dst = (which == 0) ? qo : ko;
            dst[(((size_t)(b * Hh + hd)) * Sq + s) * DHd + d] = (f16)x;
          }
        }
      }
  }
}

// ---------------------------------------------------------------------------
// Flash attention v11: v6 body BYTE-IDENTICAL, only __launch_bounds__(256,3).
//   Unified reg usage ~160 (80 VGPR + ~80 acc) <= 512/3 = 170 cap -> should
//   fit 3 waves/SIMD (12 waves/CU, 3 blocks/CU) without spilling. r5's spill
//   was the 128-reg cap of (256,4); r7's regression was the bundled row-sum
//   rewrite, not the bound. This isolates the occupancy lever on the proven
//   v6 body. Spill canary: WRITE_SIZE (16.4 MB clean).
// ---------------------------------------------------------------------------
__global__ __launch_bounds__(256, 3) void attn_v11(
    const f16* __restrict__ Qf, const f16* __restrict__ Kf,
    const f16* __restrict__ Vt, const int* __restrict__ pidr,
    const float* __restrict__ lfTab, f16* __restrict__ attf) {
  // XCD-aware decode: 1024 blocks = 8 XCDs x 128; orig id groups qb fastest.
  const int lin = blockIdx.x;
  const int orig = (lin & 7) * 128 + (lin >> 3);
  const int qb = orig & 15, hd = (orig >> 4) & 15, b = orig >> 8;
  const int bh = b * Hh + hd;
  const int tid = threadIdx.x;
  const int lane = tid & 63, w = tid >> 6;
  const int l31 = lane & 31, hi = lane >> 5;

  __shared__ __align__(16) f16 Ks[2][64 * 64];
  __shared__ __align__(16) f16 Vs[2][64 * 64];

  const size_t qkbase = (size_t)bh * Sq * DHd;   // (b,h,s,d)
  const size_t vtbase = (size_t)bh * DHd * Sq;   // (b,h,d,s)
  const int qrow = qb * 128 + w * 32 + l31;

  fh8 qf[4];
  {
    const f16* qp = &Qf[qkbase + (size_t)qrow * DHd + hi * 8];
#pragma unroll
    for (int ds = 0; ds < 4; ++ds) qf[ds] = *(const fh8*)&qp[ds * 16];
  }

  const int rq = pidr[b * Sq + qrow];
  const float* lfrow = &lfTab[((size_t)(b * NCLS + (rq + 1))) * Sq + 4 * hi];

  fh8 onesf;
#pragma unroll
  for (int j = 0; j < 8; ++j) onesf[j] = (l31 == 0) ? (f16)1.0f : (f16)0.0f;

  fx16 o_acc[2], lacc;
#pragma unroll
  for (int r = 0; r < 16; ++r) { o_acc[0][r] = 0.f; o_acc[1][r] = 0.f; lacc[r] = 0.f; }

  const int sr = tid >> 2, sc = (tid & 3) * 16;
  const int NT = Sq / 64;

  fh8 kc0, kc1, vc0, vc1;
  {
    const f16* gk = &Kf[qkbase + (size_t)sr * DHd + sc];
    kc0 = *(const fh8*)&gk[0]; kc1 = *(const fh8*)&gk[8];
    const f16* gv = &Vt[vtbase + (size_t)sr * Sq + sc];
    vc0 = *(const fh8*)&gv[0]; vc1 = *(const fh8*)&gv[8];
  }
  *(fh8*)&Ks[0][SWZ(sr, sc)]     = kc0;
  *(fh8*)&Ks[0][SWZ(sr, sc + 8)] = kc1;
  *(fh8*)&Vs[0][SWZ(sr, sc)]     = vc0;
  *(fh8*)&Vs[0][SWZ(sr, sc + 8)] = vc1;
  {
    const f16* gk = &Kf[qkbase + (size_t)(64 + sr) * DHd + sc];
    kc0 = *(const fh8*)&gk[0]; kc1 = *(const fh8*)&gk[8];
    const f16* gv = &Vt[vtbase + (size_t)sr * Sq + 64 + sc];
    vc0 = *(const fh8*)&gv[0]; vc1 = *(const fh8*)&gv[8];
  }
  __syncthreads();

  fx16 sacc0, sacc1;

  for (int kt = 0; kt < NT; ++kt) {
    const int c = kt & 1;

    {
      const float* lp = &lfrow[kt * 64];
#pragma unroll
      for (int g = 0; g < 4; ++g) {
        float4 a = *(const float4*)&lp[8 * g];
        sacc0[4 * g + 0] = a.x; sacc0[4 * g + 1] = a.y;
        sacc0[4 * g + 2] = a.z; sacc0[4 * g + 3] = a.w;
      }
    }

    if (kt + 1 < NT) {
      *(fh8*)&Ks[c ^ 1][SWZ(sr, sc)]     = kc0;
      *(fh8*)&Ks[c ^ 1][SWZ(sr, sc + 8)] = kc1;
      *(fh8*)&Vs[c ^ 1][SWZ(sr, sc)]     = vc0;
      *(fh8*)&Vs[c ^ 1][SWZ(sr, sc + 8)] = vc1;
      if (kt + 2 < NT) {
        const f16* gk = &Kf[qkbase + (size_t)((kt + 2) * 64 + sr) * DHd + sc];
        kc0 = *(const fh8*)&gk[0]; kc1 = *(const fh8*)&gk[8];
        const f16* gv = &Vt[vtbase + (size_t)sr * Sq + (kt + 2) * 64 + sc];
        vc0 = *(const fh8*)&gv[0]; vc1 = *(const fh8*)&gv[8];
      }
    }

    auto half = [&](fx16& sacc, int s, bool preload_next) {
      fh8 kfr[4];
#pragma unroll
      for (int ds = 0; ds < 4; ++ds)
        kfr[ds] = *(const fh8*)&Ks[c][SWZ(s * 32 + l31, ds * 16 + hi * 8)];
      __builtin_amdgcn_s_setprio(1);
#pragma unroll
      for (int ds = 0; ds < 4; ++ds)
        sacc = __builtin_amdgcn_mfma_f32_32x32x16_f16(kfr[ds], qf[ds], sacc, 0, 0, 0);
      __builtin_amdgcn_s_setprio(0);

      if (preload_next) {
        const float* lp = &lfrow[kt * 64 + 32];
#pragma unroll
        for (int g = 0; g < 4; ++g) {
          float4 a = *(const float4*)&lp[8 * g];
          sacc1[4 * g + 0] = a.x; sacc1[4 * g + 1] = a.y;
          sacc1[4 * g + 2] = a.z; sacc1[4 * g + 3] = a.w;
        }
      }

      int pk[8];
#pragma unroll
      for (int i = 0; i < 8; ++i) {
        fh2 h;
        h[0] = (f16)fexp2(sacc[2 * i]);
        h[1] = (f16)fexp2(sacc[2 * i + 1]);
        pk[i] = __builtin_bit_cast(int, h);
      }

      fh8 vfr[2][2];
#pragma unroll
      for (int dt = 0; dt < 2; ++dt)
#pragma unroll
        for (int kb = 0; kb < 2; ++kb)
          vfr[dt][kb] = *(const fh8*)&Vs[c][SWZ(dt * 32 + l31, s * 32 + kb * 16 + hi * 8)];

      __builtin_amdgcn_s_setprio(1);
#pragma unroll
      for (int kb = 0; kb < 2; ++kb) {
        int a01 = pk[4 * kb + 0], a23 = pk[4 * kb + 1];
        int a45 = pk[4 * kb + 2], a67 = pk[4 * kb + 3];
        i4 t;
#if __has_builtin(__builtin_amdgcn_permlane32_swap)
        auto s0 = __builtin_amdgcn_permlane32_swap(a01, a45, false, false);
        auto s1 = __builtin_amdgcn_permlane32_swap(a23, a67, false, false);
        t[0] = s0[0]; t[1] = s1[0]; t[2] = s0[1]; t[3] = s1[1];
#else
        int x01 = __shfl_xor(a01, 32), x23 = __shfl_xor(a23, 32);
        int x45 = __shfl_xor(a45, 32), x67 = __shfl_xor(a67, 32);
        t[0] = hi ? x45 : a01; t[1] = hi ? x67 : a23;
        t[2] = hi ? a45 : x01; t[3] = hi ? a67 : x23;
#endif
        fh8 pf = __builtin_bit_cast(fh8, t);
        lacc = __builtin_amdgcn_mfma_f32_32x32x16_f16(onesf, pf, lacc, 0, 0, 0);
        o_acc[0] = __builtin_amdgcn_mfma_f32_32x32x16_f16(vfr[0][kb], pf, o_acc[0], 0, 0, 0);
        o_acc[1] = __builtin_amdgcn_mfma_f32_32x32x16_f16(vfr[1][kb], pf, o_acc[1], 0, 0, 0);
      }
      __builtin_amdgcn_s_setprio(0);
    };

    half(sacc0, 0, true);
    half(sacc1, 1, false);

    if (kt + 1 < NT) __syncthreads();
  }

  float l = __shfl(lacc[0], l31);
  float inv = 1.0f / l;
  size_t obase = ((size_t)(b * Sq + qrow)) * Eq + hd * 64 + 4 * hi;
#pragma unroll
  for (int dt = 0; dt < 2; ++dt)
#pragma unroll
    for (int g = 0; g < 4; ++g) {
      fh4 o4;
#pragma unroll
      for (int j = 0; j < 4; ++j) o4[j] = (f16)(o_acc[dt][4 * g + j] * inv);
      *(fh4*)&attf[obase + dt * 32 + 8 * g] = o4;
    }
}

// ---------------------------------------------------------------------------
extern "C" void kernel_launch(void* const* d_in, const int* in_sizes, int n_in,
                              void* d_out, int out_size, void* d_ws, size_t ws_size,
                              hipStream_t stream) {
  const float* hs = (const float*)d_in[0];
  const float* rel = (const float*)d_in[1];
  const int* bnd = (const int*)d_in[2];
  const float* wi = (const float*)d_in[3];
  const float* bi = (const float*)d_in[4];
  const float* wo = (const float*)d_in[5];
  const float* bo = (const float*)d_in[6];
  float* out = (float*)d_out;

  const size_t NQ = (size_t)Bsz * Hh * Sq * DHd;  // 8,388,608 (== B*S*E)
  char* p = (char*)d_ws;
  f16* qf = (f16*)p;   p += NQ * 2;
  f16* kf = (f16*)p;   p += NQ * 2;
  f16* vt = (f16*)p;   p += NQ * 2;
  f16* hsf = (f16*)p;  p += NQ * 2;
  f16* attf = (f16*)p; p += NQ * 2;
  f16* wif = (f16*)p;  p += (size_t)3 * Eq * Eq * 2;
  f16* wof = (f16*)p;  p += (size_t)Eq * Eq * 2;
  int* pidr = (int*)p; p += Bsz * Sq * 4;
  float* lfTab = (float*)p;  // Bsz*NCLS*Sq*4 = 327KB
  // total ~93 MB < proven 134 MB footprint

  hipLaunchKernelGGL(prep, dim3(6176), dim3(256), 0, stream,
                     hs, hsf, wi, wif, wo, wof, bnd, rel, pidr, lfTab);
  hipLaunchKernelGGL((gemm_f16<1>), dim3(24, 64), dim3(256), 0, stream,
                     hsf, wif, bi, (float*)nullptr, Bsz * Sq, 3 * Eq, Eq,
                     qf, kf, vt);
  hipLaunchKernelGGL(attn_v11, dim3(16 * 16 * 4), dim3(256), 0, stream,
                     qf, kf, vt, pidr, lfTab, attf);
  hipLaunchKernelGGL((gemm_f16<0>), dim3(8, 64), dim3(256), 0, stream,
                     attf, wof, bo, out, Bsz * Sq, Eq, Eq,
                     nullptr, nullptr, nullptr);
}

// Round 17
// 295.101 us; speedup vs baseline: 1.0616x; 1.0065x over previous
//
#include <hip/hip_runtime.h>
#include <math.h>

#define Bsz 4
#define Sq  2048
#define Eq  1024
#define Hh  16
#define DHd 64
#define Kb  9
#define LOG2E 1.44269504088896340736f
#define NCLS 10  // row classes: query(-1) + pids 0..8

typedef _Float16 f16;
typedef __attribute__((ext_vector_type(8))) _Float16 fh8;   // MFMA A/B frag (4 VGPRs)
typedef __attribute__((ext_vector_type(4))) _Float16 fh4;
typedef __attribute__((ext_vector_type(2))) _Float16 fh2;
typedef __attribute__((ext_vector_type(4))) float fx4;      // 16x16 C/D frag
typedef __attribute__((ext_vector_type(16))) float fx16;    // 32x32 C/D frag
typedef __attribute__((ext_vector_type(4))) int i4;

// LDS swizzle: 64-half rows (128 B) -> XOR row into 16B-chunk index.
#define SWZ(r, c) ((r) * 64 + ((c) ^ (((r) & 7) << 3)))

static __device__ __forceinline__ float fexp2(float x) {
#if __has_builtin(__builtin_amdgcn_exp2f)
  return __builtin_amdgcn_exp2f(x);   // raw v_exp_f32
#else
  return __expf(x * 0.6931471805599453f);
#endif
}

// ---------------------------------------------------------------------------
// prep: fused pid/lfTab build + fp32->fp16 casts of hs, wi, wo (one launch).
// ---------------------------------------------------------------------------
__global__ __launch_bounds__(256) void prep(
    const float* __restrict__ hs, f16* __restrict__ hsf,
    const float* __restrict__ wi, f16* __restrict__ wif,
    const float* __restrict__ wo, f16* __restrict__ wof,
    const int* __restrict__ bnd, const float* __restrict__ rel,
    int* __restrict__ pidr, float* __restrict__ lfTab) {
  const int bid = blockIdx.x;
  if (bid < 6144) {
    const float* src;
    f16* dst;
    int off;
    if (bid < 4096)      { src = hs; dst = hsf; off = bid; }
    else if (bid < 5632) { src = wi; dst = wif; off = bid - 4096; }
    else                 { src = wo; dst = wof; off = bid - 5632; }
    int i = (off * 256 + threadIdx.x) * 8;
    float4 a = *(const float4*)&src[i];
    float4 b = *(const float4*)&src[i + 4];
    fh8 o;
    o[0] = (f16)a.x; o[1] = (f16)a.y; o[2] = (f16)a.z; o[3] = (f16)a.w;
    o[4] = (f16)b.x; o[5] = (f16)b.y; o[6] = (f16)b.z; o[7] = (f16)b.w;
    *(fh8*)&dst[i] = o;
  } else {
    int idx = (bid - 6144) * 256 + threadIdx.x;
    if (idx >= Bsz * Sq) return;
    int b = idx >> 11;
    int s = idx & (Sq - 1);
    int j = -1;
#pragma unroll
    for (int t = 0; t < Kb; ++t) {
      if (bnd[b * Kb + t] <= s) j = t;
    }
    pidr[idx] = j;
    bool inp = (j >= 0 && j < Kb - 1);
    float cv = inp ? rel[b * (Kb - 1) + j] : 1.0f;
    float* base = &lfTab[(size_t)b * NCLS * Sq + s];
    base[0] = cv * LOG2E;  // query-row class
#pragma unroll
    for (int c = 1; c < NCLS; ++c)
      base[c * Sq] = (inp && j == c - 1) ? LOG2E : 0.0f;
  }
}

// ---------------------------------------------------------------------------
// fp16 MFMA GEMM (r6/r11-proven config): C = A * B^T + bias.
//   128x128x64 tile, 4 waves 2x2, 16x16x32 MFMA.
//   Register-prefetch pipeline + XOR-swizzled 32 KB LDS, plain __syncthreads.
// MODE 0: Cp[m*N+n] = acc + bias (fp32)
// MODE 1: n<1024 -> q fp16 scaled 0.125*log2e; n<2048 -> k fp16; else vt fp16^T
// ---------------------------------------------------------------------------
template <int MODE>
__global__ __launch_bounds__(256) void gemm_f16(
    const f16* __restrict__ A, const f16* __restrict__ Bh,
    const float* __restrict__ bias, float* __restrict__ Cp,
    int M, int N, int Kd,
    f16* __restrict__ qo, f16* __restrict__ ko, f16* __restrict__ vto) {
  __shared__ __align__(16) f16 Ash[128 * 64];
  __shared__ __align__(16) f16 Bsh[128 * 64];

  const int tid = threadIdx.x;
  const int lane = tid & 63, w = tid >> 6;
  const int wm = w >> 1, wn = w & 1;
  const int q16 = lane & 15, quad = lane >> 4;
  const int m_blk = blockIdx.y * 128, n_blk = blockIdx.x * 128;

  fx4 acc[4][4];
#pragma unroll
  for (int mt = 0; mt < 4; ++mt)
#pragma unroll
    for (int nt = 0; nt < 4; ++nt)
#pragma unroll
      for (int r = 0; r < 4; ++r) acc[mt][nt][r] = 0.f;

  const int sr = tid >> 2, sc = (tid & 3) * 16;

  // register-prefetch buffers: [row-half][16B chunk]
  fh8 pa[2][2], pb[2][2];
  const f16* ga0 = &A[(size_t)(m_blk + sr) * Kd + sc];
  const f16* gb0 = &Bh[(size_t)(n_blk + sr) * Kd + sc];

#pragma unroll
  for (int h = 0; h < 2; ++h) {
    const f16* ga = ga0 + (size_t)h * 64 * Kd;
    pa[h][0] = *(const fh8*)&ga[0];
    pa[h][1] = *(const fh8*)&ga[8];
    const f16* gb = gb0 + (size_t)h * 64 * Kd;
    pb[h][0] = *(const fh8*)&gb[0];
    pb[h][1] = *(const fh8*)&gb[8];
  }

  for (int k0 = 0; k0 < Kd; k0 += 64) {
    __syncthreads();  // prior iteration's LDS frag reads complete
#pragma unroll
    for (int h = 0; h < 2; ++h) {
      const int r = sr + h * 64;
      *(fh8*)&Ash[SWZ(r, sc)]     = pa[h][0];
      *(fh8*)&Ash[SWZ(r, sc + 8)] = pa[h][1];
      *(fh8*)&Bsh[SWZ(r, sc)]     = pb[h][0];
      *(fh8*)&Bsh[SWZ(r, sc + 8)] = pb[h][1];
    }
    if (k0 + 64 < Kd) {  // issue next K-step loads; in flight during MFMA
      const int kn = k0 + 64;
#pragma unroll
      for (int h = 0; h < 2; ++h) {
        const f16* ga = ga0 + (size_t)h * 64 * Kd + kn;
        pa[h][0] = *(const fh8*)&ga[0];
        pa[h][1] = *(const fh8*)&ga[8];
        const f16* gb = gb0 + (size_t)h * 64 * Kd + kn;
        pb[h][0] = *(const fh8*)&gb[0];
        pb[h][1] = *(const fh8*)&gb[8];
      }
    }
    __syncthreads();

#pragma unroll
    for (int ks = 0; ks < 2; ++ks) {
      fh8 af[4], bfr[4];
#pragma unroll
      for (int mt = 0; mt < 4; ++mt)
        af[mt] = *(const fh8*)&Ash[SWZ(wm * 64 + mt * 16 + q16, ks * 32 + quad * 8)];
#pragma unroll
      for (int nt = 0; nt < 4; ++nt)
        bfr[nt] = *(const fh8*)&Bsh[SWZ(wn * 64 + nt * 16 + q16, ks * 32 + quad * 8)];
#pragma unroll
      for (int nt = 0; nt < 4; ++nt)
#pragma unroll
        for (int mt = 0; mt < 4; ++mt)
          acc[mt][nt] = __builtin_amdgcn_mfma_f32_16x16x32_f16(af[mt], bfr[nt], acc[mt][nt], 0, 0, 0);
    }
  }

  float bsv[4];
#pragma unroll
  for (int nt = 0; nt < 4; ++nt) bsv[nt] = bias[n_blk + wn * 64 + nt * 16 + q16];

  if (MODE == 0) {
#pragma unroll
    for (int mt = 0; mt < 4; ++mt)
#pragma unroll
      for (int r = 0; r < 4; ++r) {
        int row = m_blk + wm * 64 + mt * 16 + quad * 4 + r;
#pragma unroll
        for (int nt = 0; nt < 4; ++nt) {
          int col = n_blk + wn * 64 + nt * 16 + q16;
          Cp[(size_t)row * N + col] = acc[mt][nt][r] + bsv[nt];
        }
      }
  } else {
    const int n0 = n_blk + wn * 64;  // 64-aligned -> which/hd wave-uniform
    const int which = n0 >> 10;
    const int hd = (n0 & 1023) >> 6;
    const float scale = (which == 0) ? 0.125f * LOG2E : 1.0f;
#pragma unroll
    for (int mt = 0; mt < 4; ++mt)
#pragma unroll
      for (int r = 0; r < 4; ++r) {
        int m = m_blk + wm * 64 + mt * 16 + quad * 4 + r;
        int b = m >> 11, s = m & (Sq - 1);
#pragma unroll
        for (int nt = 0; nt < 4; ++nt) {
          int d = nt * 16 + q16;
          float x = (acc[mt][nt][r] + bsv[nt]) * scale;
          if (which == 2) {  // V transposed: (B,H,DH,S)
            vto[(((size_t)(b * Hh + hd)) * DHd + d) * Sq + s] = (f16)x;
          } else {
            f16* dst = (which == 0) ? qo : ko;
            dst[(((size_t)(b * Hh + hd)) * Sq + s) * DHd + d] = (f16)x;
          }
        }
      }
  }
}

// ---------------------------------------------------------------------------
// Flash attention v6 (r11-proven, 103.4 us): swapped-QK 32x32 MFMA, register-
// resident P, raw v_exp_f32, mask as MFMA C-init, ones-row MFMA row-sum,
// double-buffered LDS, XCD-swizzled 1D grid, setprio around MFMA clusters.
// (256,2): proven no-spill configuration; (256,3) was ignored by the
// allocator (r16: VGPR/occupancy unchanged) and (256,4) spilled (r5).
// ---------------------------------------------------------------------------
__global__ __launch_bounds__(256, 2) void attn_v6(
    const f16* __restrict__ Qf, const f16* __restrict__ Kf,
    const f16* __restrict__ Vt, const int* __restrict__ pidr,
    const float* __restrict__ lfTab, f16* __restrict__ attf) {
  // XCD-aware decode: 1024 blocks = 8 XCDs x 128; orig id groups qb fastest.
  const int lin = blockIdx.x;
  const int orig = (lin & 7) * 128 + (lin >> 3);
  const int qb = orig & 15, hd = (orig >> 4) & 15, b = orig >> 8;
  const int bh = b * Hh + hd;
  const int tid = threadIdx.x;
  const int lane = tid & 63, w = tid >> 6;
  const int l31 = lane & 31, hi = lane >> 5;

  __shared__ __align__(16) f16 Ks[2][64 * 64];
  __shared__ __align__(16) f16 Vs[2][64 * 64];

  const size_t qkbase = (size_t)bh * Sq * DHd;   // (b,h,s,d)
  const size_t vtbase = (size_t)bh * DHd * Sq;   // (b,h,d,s)
  const int qrow = qb * 128 + w * 32 + l31;

  fh8 qf[4];
  {
    const f16* qp = &Qf[qkbase + (size_t)qrow * DHd + hi * 8];
#pragma unroll
    for (int ds = 0; ds < 4; ++ds) qf[ds] = *(const fh8*)&qp[ds * 16];
  }

  const int rq = pidr[b * Sq + qrow];
  const float* lfrow = &lfTab[((size_t)(b * NCLS + (rq + 1))) * Sq + 4 * hi];

  fh8 onesf;
#pragma unroll
  for (int j = 0; j < 8; ++j) onesf[j] = (l31 == 0) ? (f16)1.0f : (f16)0.0f;

  fx16 o_acc[2], lacc;
#pragma unroll
  for (int r = 0; r < 16; ++r) { o_acc[0][r] = 0.f; o_acc[1][r] = 0.f; lacc[r] = 0.f; }

  const int sr = tid >> 2, sc = (tid & 3) * 16;
  const int NT = Sq / 64;

  fh8 kc0, kc1, vc0, vc1;
  {
    const f16* gk = &Kf[qkbase + (size_t)sr * DHd + sc];
    kc0 = *(const fh8*)&gk[0]; kc1 = *(const fh8*)&gk[8];
    const f16* gv = &Vt[vtbase + (size_t)sr * Sq + sc];
    vc0 = *(const fh8*)&gv[0]; vc1 = *(const fh8*)&gv[8];
  }
  *(fh8*)&Ks[0][SWZ(sr, sc)]     = kc0;
  *(fh8*)&Ks[0][SWZ(sr, sc + 8)] = kc1;
  *(fh8*)&Vs[0][SWZ(sr, sc)]     = vc0;
  *(fh8*)&Vs[0][SWZ(sr, sc + 8)] = vc1;
  {
    const f16* gk = &Kf[qkbase + (size_t)(64 + sr) * DHd + sc];
    kc0 = *(const fh8*)&gk[0]; kc1 = *(const fh8*)&gk[8];
    const f16* gv = &Vt[vtbase + (size_t)sr * Sq + 64 + sc];
    vc0 = *(const fh8*)&gv[0]; vc1 = *(const fh8*)&gv[8];
  }
  __syncthreads();

  fx16 sacc0, sacc1;

  for (int kt = 0; kt < NT; ++kt) {
    const int c = kt & 1;

    {
      const float* lp = &lfrow[kt * 64];
#pragma unroll
      for (int g = 0; g < 4; ++g) {
        float4 a = *(const float4*)&lp[8 * g];
        sacc0[4 * g + 0] = a.x; sacc0[4 * g + 1] = a.y;
        sacc0[4 * g + 2] = a.z; sacc0[4 * g + 3] = a.w;
      }
    }

    if (kt + 1 < NT) {
      *(fh8*)&Ks[c ^ 1][SWZ(sr, sc)]     = kc0;
      *(fh8*)&Ks[c ^ 1][SWZ(sr, sc + 8)] = kc1;
      *(fh8*)&Vs[c ^ 1][SWZ(sr, sc)]     = vc0;
      *(fh8*)&Vs[c ^ 1][SWZ(sr, sc + 8)] = vc1;
      if (kt + 2 < NT) {
        const f16* gk = &Kf[qkbase + (size_t)((kt + 2) * 64 + sr) * DHd + sc];
        kc0 = *(const fh8*)&gk[0]; kc1 = *(const fh8*)&gk[8];
        const f16* gv = &Vt[vtbase + (size_t)sr * Sq + (kt + 2) * 64 + sc];
        vc0 = *(const fh8*)&gv[0]; vc1 = *(const fh8*)&gv[8];
      }
    }

    auto half = [&](fx16& sacc, int s, bool preload_next) {
      fh8 kfr[4];
#pragma unroll
      for (int ds = 0; ds < 4; ++ds)
        kfr[ds] = *(const fh8*)&Ks[c][SWZ(s * 32 + l31, ds * 16 + hi * 8)];
      __builtin_amdgcn_s_setprio(1);
#pragma unroll
      for (int ds = 0; ds < 4; ++ds)
        sacc = __builtin_amdgcn_mfma_f32_32x32x16_f16(kfr[ds], qf[ds], sacc, 0, 0, 0);
      __builtin_amdgcn_s_setprio(0);

      if (preload_next) {
        const float* lp = &lfrow[kt * 64 + 32];
#pragma unroll
        for (int g = 0; g < 4; ++g) {
          float4 a = *(const float4*)&lp[8 * g];
          sacc1[4 * g + 0] = a.x; sacc1[4 * g + 1] = a.y;
          sacc1[4 * g + 2] = a.z; sacc1[4 * g + 3] = a.w;
        }
      }

      int pk[8];
#pragma unroll
      for (int i = 0; i < 8; ++i) {
        fh2 h;
        h[0] = (f16)fexp2(sacc[2 * i]);
        h[1] = (f16)fexp2(sacc[2 * i + 1]);
        pk[i] = __builtin_bit_cast(int, h);
      }

      fh8 vfr[2][2];
#pragma unroll
      for (int dt = 0; dt < 2; ++dt)
#pragma unroll
        for (int kb = 0; kb < 2; ++kb)
          vfr[dt][kb] = *(const fh8*)&Vs[c][SWZ(dt * 32 + l31, s * 32 + kb * 16 + hi * 8)];

      __builtin_amdgcn_s_setprio(1);
#pragma unroll
      for (int kb = 0; kb < 2; ++kb) {
        int a01 = pk[4 * kb + 0], a23 = pk[4 * kb + 1];
        int a45 = pk[4 * kb + 2], a67 = pk[4 * kb + 3];
        i4 t;
#if __has_builtin(__builtin_amdgcn_permlane32_swap)
        auto s0 = __builtin_amdgcn_permlane32_swap(a01, a45, false, false);
        auto s1 = __builtin_amdgcn_permlane32_swap(a23, a67, false, false);
        t[0] = s0[0]; t[1] = s1[0]; t[2] = s0[1]; t[3] = s1[1];
#else
        int x01 = __shfl_xor(a01, 32), x23 = __shfl_xor(a23, 32);
        int x45 = __shfl_xor(a45, 32), x67 = __shfl_xor(a67, 32);
        t[0] = hi ? x45 : a01; t[1] = hi ? x67 : a23;
        t[2] = hi ? a45 : x01; t[3] = hi ? a67 : x23;
#endif
        fh8 pf = __builtin_bit_cast(fh8, t);
        lacc = __builtin_amdgcn_mfma_f32_32x32x16_f16(onesf, pf, lacc, 0, 0, 0);
        o_acc[0] = __builtin_amdgcn_mfma_f32_32x32x16_f16(vfr[0][kb], pf, o_acc[0], 0, 0, 0);
        o_acc[1] = __builtin_amdgcn_mfma_f32_32x32x16_f16(vfr[1][kb], pf, o_acc[1], 0, 0, 0);
      }
      __builtin_amdgcn_s_setprio(0);
    };

    half(sacc0, 0, true);
    half(sacc1, 1, false);

    if (kt + 1 < NT) __syncthreads();
  }

  float l = __shfl(lacc[0], l31);
  float inv = 1.0f / l;
  size_t obase = ((size_t)(b * Sq + qrow)) * Eq + hd * 64 + 4 * hi;
#pragma unroll
  for (int dt = 0; dt < 2; ++dt)
#pragma unroll
    for (int g = 0; g < 4; ++g) {
      fh4 o4;
#pragma unroll
      for (int j = 0; j < 4; ++j) o4[j] = (f16)(o_acc[dt][4 * g + j] * inv);
      *(fh4*)&attf[obase + dt * 32 + 8 * g] = o4;
    }
}

// ---------------------------------------------------------------------------
extern "C" void kernel_launch(void* const* d_in, const int* in_sizes, int n_in,
                              void* d_out, int out_size, void* d_ws, size_t ws_size,
                              hipStream_t stream) {
  const float* hs = (const float*)d_in[0];
  const float* rel = (const float*)d_in[1];
  const int* bnd = (const int*)d_in[2];
  const float* wi = (const float*)d_in[3];
  const float* bi = (const float*)d_in[4];
  const float* wo = (const float*)d_in[5];
  const float* bo = (const float*)d_in[6];
  float* out = (float*)d_out;

  const size_t NQ = (size_t)Bsz * Hh * Sq * DHd;  // 8,388,608 (== B*S*E)
  char* p = (char*)d_ws;
  f16* qf = (f16*)p;   p += NQ * 2;
  f16* kf = (f16*)p;   p += NQ * 2;
  f16* vt = (f16*)p;   p += NQ * 2;
  f16* hsf = (f16*)p;  p += NQ * 2;
  f16* attf = (f16*)p; p += NQ * 2;
  f16* wif = (f16*)p;  p += (size_t)3 * Eq * Eq * 2;
  f16* wof = (f16*)p;  p += (size_t)Eq * Eq * 2;
  int* pidr = (int*)p; p += Bsz * Sq * 4;
  float* lfTab = (float*)p;  // Bsz*NCLS*Sq*4 = 327KB
  // total ~93 MB < proven 134 MB footprint

  hipLaunchKernelGGL(prep, dim3(6176), dim3(256), 0, stream,
                     hs, hsf, wi, wif, wo, wof, bnd, rel, pidr, lfTab);
  hipLaunchKernelGGL((gemm_f16<1>), dim3(24, 64), dim3(256), 0, stream,
                     hsf, wif, bi, (float*)nullptr, Bsz * Sq, 3 * Eq, Eq,
                     qf, kf, vt);
  hipLaunchKernelGGL(attn_v6, dim3(16 * 16 * 4), dim3(256), 0, stream,
                     qf, kf, vt, pidr, lfTab, attf);
  hipLaunchKernelGGL((gemm_f16<0>), dim3(8, 64), dim3(256), 0, stream,
                     attf, wof, bo, out, Bsz * Sq, Eq, Eq,
                     nullptr, nullptr, nullptr);
}